// Round 3
// baseline (403.528 us; speedup 1.0000x reference)
//
#include <hip/hip_runtime.h>
#include <hip/hip_bf16.h>
#include <hip/hip_fp16.h>

#define DIM 64

// ---------------------------------------------------------------------------
// Detect whether edge_index arrived as int64 (high dwords of first 64 values
// all zero) or int32. Parallel: one wave, one ballot. Runs every call.
// ---------------------------------------------------------------------------
__global__ void detect_kernel(const unsigned int* __restrict__ ei, int* __restrict__ flag) {
    const int lane = threadIdx.x & 63;
    const unsigned int hi = ei[2 * lane + 1];
    const unsigned long long ball = __ballot(hi != 0u);
    if (threadIdx.x == 0) *flag = (ball == 0ULL) ? 1 : 0;
}

// ---------------------------------------------------------------------------
// Convert x (f32) -> xh (fp16), vectorized float4 -> ushort4.
// ---------------------------------------------------------------------------
__global__ void __launch_bounds__(256) convert_kernel(
    const float4* __restrict__ x, ushort4* __restrict__ xh, int n4) {
    const int i = blockIdx.x * 256 + threadIdx.x;
    if (i >= n4) return;
    const float4 v = x[i];
    ushort4 o;
    o.x = __half_as_ushort(__float2half(v.x));
    o.y = __half_as_ushort(__float2half(v.y));
    o.z = __half_as_ushort(__float2half(v.z));
    o.w = __half_as_ushort(__float2half(v.w));
    xh[i] = o;
}

// ---------------------------------------------------------------------------
// Histogram of destination rows (int atomics), 4 edges per thread.
// ---------------------------------------------------------------------------
__global__ void __launch_bounds__(256) hist_kernel(
    const void* __restrict__ eiv, int* __restrict__ cnt,
    int nE, const int* __restrict__ flag) {
    const int base = (blockIdx.x * 256 + threadIdx.x) * 4;
    if (base >= nE) return;
    if (*flag) {
        const long long* ei = (const long long*)eiv;
        #pragma unroll
        for (int k = 0; k < 4; ++k)
            if (base + k < nE) atomicAdd(&cnt[(int)ei[base + k]], 1);
    } else {
        const int* ei = (const int*)eiv;
        #pragma unroll
        for (int k = 0; k < 4; ++k)
            if (base + k < nE) atomicAdd(&cnt[ei[base + k]], 1);
    }
}

// ---------------------------------------------------------------------------
// Exclusive scan, hierarchical (1024 elems/block).
// ---------------------------------------------------------------------------
__global__ void __launch_bounds__(256) scan1_kernel(
    const int* __restrict__ cnt, int* __restrict__ cursor,
    int* __restrict__ blksums, int n) {
    __shared__ int tmp[256];
    const int t = threadIdx.x;
    const int base = blockIdx.x * 1024 + t * 4;
    int v0 = (base + 0 < n) ? cnt[base + 0] : 0;
    int v1 = (base + 1 < n) ? cnt[base + 1] : 0;
    int v2 = (base + 2 < n) ? cnt[base + 2] : 0;
    int v3 = (base + 3 < n) ? cnt[base + 3] : 0;
    const int s = v0 + v1 + v2 + v3;
    tmp[t] = s;
    __syncthreads();
    for (int off = 1; off < 256; off <<= 1) {
        int v = 0;
        if (t >= off) v = tmp[t - off];
        __syncthreads();
        tmp[t] += v;
        __syncthreads();
    }
    const int excl = tmp[t] - s;
    if (t == 255) blksums[blockIdx.x] = tmp[255];
    if (base + 0 < n) cursor[base + 0] = excl;
    if (base + 1 < n) cursor[base + 1] = excl + v0;
    if (base + 2 < n) cursor[base + 2] = excl + v0 + v1;
    if (base + 3 < n) cursor[base + 3] = excl + v0 + v1 + v2;
}

__global__ void __launch_bounds__(1024) scan2_kernel(int* __restrict__ blksums, int nblk) {
    __shared__ int tmp[1024];
    const int t = threadIdx.x;
    const int v = (t < nblk) ? blksums[t] : 0;
    tmp[t] = v;
    __syncthreads();
    for (int off = 1; off < 1024; off <<= 1) {
        int u = 0;
        if (t >= off) u = tmp[t - off];
        __syncthreads();
        tmp[t] += u;
        __syncthreads();
    }
    if (t < nblk) blksums[t] = tmp[t] - v;
}

__global__ void __launch_bounds__(256) scan3_kernel(
    int* __restrict__ cursor, const int* __restrict__ blksums, int n) {
    const int add = blksums[blockIdx.x];
    const int base = blockIdx.x * 1024 + threadIdx.x * 4;
    if (base + 0 < n) cursor[base + 0] += add;
    if (base + 1 < n) cursor[base + 1] += add;
    if (base + 2 < n) cursor[base + 2] += add;
    if (base + 3 < n) cursor[base + 3] += add;
}

// ---------------------------------------------------------------------------
// CSR build: place each edge's col into its row's segment, 2 edges/thread.
// After this kernel, cursor[r] == segment end for row r.
// ---------------------------------------------------------------------------
__global__ void __launch_bounds__(256) build_kernel(
    const void* __restrict__ eiv, int* __restrict__ cursor,
    int* __restrict__ scol, int nE, const int* __restrict__ flag) {
    const int base = (blockIdx.x * 256 + threadIdx.x) * 2;
    if (base >= nE) return;
    int r0 = -1, c0 = 0, r1 = -1, c1 = 0;
    if (*flag) {
        const long long* ei = (const long long*)eiv;
        r0 = (int)ei[base]; c0 = (int)ei[nE + base];
        if (base + 1 < nE) { r1 = (int)ei[base + 1]; c1 = (int)ei[nE + base + 1]; }
    } else {
        const int* ei = (const int*)eiv;
        r0 = ei[base]; c0 = ei[nE + base];
        if (base + 1 < nE) { r1 = ei[base + 1]; c1 = ei[nE + base + 1]; }
    }
    const int p0 = atomicAdd(&cursor[r0], 1);
    int p1 = -1;
    if (r1 >= 0) p1 = atomicAdd(&cursor[r1], 1);
    scol[p0] = c0;
    if (p1 >= 0) scol[p1] = c1;
}

// ---------------------------------------------------------------------------
// Fused gather (fp16) + mean + (row @ W^T + b). One wave per node.
// ---------------------------------------------------------------------------
__global__ void __launch_bounds__(256) gather_finalize_kernel(
    const __half* __restrict__ xh, const int* __restrict__ scol,
    const int* __restrict__ cursor, const int* __restrict__ cnt,
    const float* __restrict__ W, const float* __restrict__ b,
    float* __restrict__ out, int n) {
    __shared__ __align__(16) float rowbuf[4][DIM];
    const int group = threadIdx.x >> 6;
    const int lane  = threadIdx.x & 63;
    const int wid   = (int)((blockIdx.x * blockDim.x + threadIdx.x) >> 6);
    const int nw    = (int)((gridDim.x * blockDim.x) >> 6);

    // wc[k] = W[lane][k]  (thread's output column of W^T)
    float wc[DIM];
    #pragma unroll
    for (int k4 = 0; k4 < DIM / 4; ++k4) {
        float4 w4 = *(const float4*)&W[(size_t)lane * DIM + k4 * 4];
        wc[k4 * 4 + 0] = w4.x; wc[k4 * 4 + 1] = w4.y;
        wc[k4 * 4 + 2] = w4.z; wc[k4 * 4 + 3] = w4.w;
    }
    const float bl = b[lane];

    for (int r = wid; r < n; r += nw) {
        const int k   = cnt[r];
        const int end = cursor[r];
        const int s   = end - k;
        float a0 = 0.0f, a1 = 0.0f;
        int j = 0;
        for (; j + 3 < k; j += 4) {
            const int c0 = scol[s + j + 0];
            const int c1 = scol[s + j + 1];
            const int c2 = scol[s + j + 2];
            const int c3 = scol[s + j + 3];
            const float v0 = __half2float(xh[(size_t)c0 * DIM + lane]);
            const float v1 = __half2float(xh[(size_t)c1 * DIM + lane]);
            const float v2 = __half2float(xh[(size_t)c2 * DIM + lane]);
            const float v3 = __half2float(xh[(size_t)c3 * DIM + lane]);
            a0 += v0; a1 += v1; a0 += v2; a1 += v3;
        }
        for (; j < k; ++j) {
            const int c = scol[s + j];
            a0 += __half2float(xh[(size_t)c * DIM + lane]);
        }
        const float dg   = (k > 0) ? (float)k : 1.0f;
        const float mean = (a0 + a1) / dg;

        rowbuf[group][lane] = mean;   // per-wave broadcast; DS ops in wave order
        float dot = bl;
        #pragma unroll
        for (int k4 = 0; k4 < DIM / 4; ++k4) {
            const float4 m4 = *(const float4*)&rowbuf[group][k4 * 4];
            dot += m4.x * wc[k4 * 4 + 0];
            dot += m4.y * wc[k4 * 4 + 1];
            dot += m4.z * wc[k4 * 4 + 2];
            dot += m4.w * wc[k4 * 4 + 3];
        }
        out[(size_t)r * DIM + lane] = dot;
    }
}

// f32 gather variant (fallback if ws can't hold xh)
__global__ void __launch_bounds__(256) gather_finalize_f32_kernel(
    const float* __restrict__ x, const int* __restrict__ scol,
    const int* __restrict__ cursor, const int* __restrict__ cnt,
    const float* __restrict__ W, const float* __restrict__ b,
    float* __restrict__ out, int n) {
    __shared__ __align__(16) float rowbuf[4][DIM];
    const int group = threadIdx.x >> 6;
    const int lane  = threadIdx.x & 63;
    const int wid   = (int)((blockIdx.x * blockDim.x + threadIdx.x) >> 6);
    const int nw    = (int)((gridDim.x * blockDim.x) >> 6);
    float wc[DIM];
    #pragma unroll
    for (int k4 = 0; k4 < DIM / 4; ++k4) {
        float4 w4 = *(const float4*)&W[(size_t)lane * DIM + k4 * 4];
        wc[k4 * 4 + 0] = w4.x; wc[k4 * 4 + 1] = w4.y;
        wc[k4 * 4 + 2] = w4.z; wc[k4 * 4 + 3] = w4.w;
    }
    const float bl = b[lane];
    for (int r = wid; r < n; r += nw) {
        const int k   = cnt[r];
        const int end = cursor[r];
        const int s   = end - k;
        float a0 = 0.0f, a1 = 0.0f;
        int j = 0;
        for (; j + 3 < k; j += 4) {
            const int c0 = scol[s + j + 0];
            const int c1 = scol[s + j + 1];
            const int c2 = scol[s + j + 2];
            const int c3 = scol[s + j + 3];
            a0 += x[(size_t)c0 * DIM + lane];
            a1 += x[(size_t)c1 * DIM + lane];
            a0 += x[(size_t)c2 * DIM + lane];
            a1 += x[(size_t)c3 * DIM + lane];
        }
        for (; j < k; ++j) a0 += x[(size_t)scol[s + j] * DIM + lane];
        const float dg   = (k > 0) ? (float)k : 1.0f;
        const float mean = (a0 + a1) / dg;
        rowbuf[group][lane] = mean;
        float dot = bl;
        #pragma unroll
        for (int k4 = 0; k4 < DIM / 4; ++k4) {
            const float4 m4 = *(const float4*)&rowbuf[group][k4 * 4];
            dot += m4.x * wc[k4 * 4 + 0];
            dot += m4.y * wc[k4 * 4 + 1];
            dot += m4.z * wc[k4 * 4 + 2];
            dot += m4.w * wc[k4 * 4 + 3];
        }
        out[(size_t)r * DIM + lane] = dot;
    }
}

extern "C" void kernel_launch(void* const* d_in, const int* in_sizes, int n_in,
                              void* d_out, int out_size, void* d_ws, size_t ws_size,
                              hipStream_t stream) {
    const float* x  = (const float*)d_in[0];
    const void*  ei = (const void*)d_in[1];
    const float* W  = (const float*)d_in[2];
    const float* b  = (const float*)d_in[3];
    float* out = (float*)d_out;

    const int n  = in_sizes[0] / DIM;   // 100000
    const int nE = in_sizes[1] / 2;     // 1600000

    // ws layout (4B units): cnt[n] | cursor[n] | blksums[1024] | flag[64] | scol[nE] | xh[n*32]
    int* wsI     = (int*)d_ws;
    int* cnt     = wsI;
    int* cursor  = wsI + n;
    int* blksums = wsI + 2 * n;
    int* flag    = wsI + 2 * n + 1024;
    int* scol    = wsI + 2 * n + 1088;
    __half* xh   = (__half*)(wsI + 2 * n + 1088 + nE);
    const size_t need_csr  = ((size_t)2 * n + 1088 + (size_t)nE) * sizeof(int);
    const size_t need_fp16 = need_csr + (size_t)n * DIM * sizeof(__half);

    if (ws_size >= need_csr) {
        const int nblk = (n + 1023) / 1024;   // 98
        detect_kernel<<<1, 64, 0, stream>>>((const unsigned int*)ei, flag);
        hipMemsetAsync(cnt, 0, (size_t)n * sizeof(int), stream);
        const bool fp16 = (ws_size >= need_fp16);
        if (fp16) {
            const int n4 = n * DIM / 4;
            convert_kernel<<<(n4 + 255) / 256, 256, 0, stream>>>(
                (const float4*)x, (ushort4*)xh, n4);
        }
        hist_kernel <<<(nE / 4 + 255) / 256, 256, 0, stream>>>(ei, cnt, nE, flag);
        scan1_kernel<<<nblk, 256, 0, stream>>>(cnt, cursor, blksums, n);
        scan2_kernel<<<1, 1024, 0, stream>>>(blksums, nblk);
        scan3_kernel<<<nblk, 256, 0, stream>>>(cursor, blksums, n);
        build_kernel<<<(nE / 2 + 255) / 256, 256, 0, stream>>>(ei, cursor, scol, nE, flag);
        if (fp16) {
            gather_finalize_kernel<<<2048, 256, 0, stream>>>(xh, scol, cursor, cnt, W, b, out, n);
        } else {
            gather_finalize_f32_kernel<<<2048, 256, 0, stream>>>(x, scol, cursor, cnt, W, b, out, n);
        }
    }
}

// Round 4
// 352.895 us; speedup vs baseline: 1.1435x; 1.1435x over previous
//
#include <hip/hip_runtime.h>
#include <hip/hip_bf16.h>
#include <hip/hip_fp16.h>

#define DIM 64
#define NPART 8

// ---------------------------------------------------------------------------
// Detect whether edge_index arrived as int64 (high dwords of first 64 values
// all zero) or int32. Parallel: one wave, one ballot. Runs every call.
// ---------------------------------------------------------------------------
__global__ void detect_kernel(const unsigned int* __restrict__ ei, int* __restrict__ flag) {
    const int lane = threadIdx.x & 63;
    const unsigned int hi = ei[2 * lane + 1];
    const unsigned long long ball = __ballot(hi != 0u);
    if (threadIdx.x == 0) *flag = (ball == 0ULL) ? 1 : 0;
}

// ---------------------------------------------------------------------------
// Convert edge_index to packed int32 rows32/cols32 (works for either dtype).
// ---------------------------------------------------------------------------
__global__ void __launch_bounds__(256) cvt_idx_kernel(
    const void* __restrict__ eiv, int* __restrict__ rows32, int* __restrict__ cols32,
    int nE, const int* __restrict__ flag) {
    const int e = blockIdx.x * 256 + threadIdx.x;
    if (e >= nE) return;
    if (*flag) {
        const long long* ei = (const long long*)eiv;
        rows32[e] = (int)ei[e];
        cols32[e] = (int)ei[nE + e];
    } else {
        const int* ei = (const int*)eiv;
        rows32[e] = ei[e];
        cols32[e] = ei[nE + e];
    }
}

// ---------------------------------------------------------------------------
// Convert x (f32) -> xh (fp16), vectorized float4 -> ushort4.
// ---------------------------------------------------------------------------
__global__ void __launch_bounds__(256) convert_kernel(
    const float4* __restrict__ x, ushort4* __restrict__ xh, int n4) {
    const int i = blockIdx.x * 256 + threadIdx.x;
    if (i >= n4) return;
    const float4 v = x[i];
    ushort4 o;
    o.x = __half_as_ushort(__float2half(v.x));
    o.y = __half_as_ushort(__float2half(v.y));
    o.z = __half_as_ushort(__float2half(v.z));
    o.w = __half_as_ushort(__float2half(v.w));
    xh[i] = o;
}

// ---------------------------------------------------------------------------
// Histogram of destination rows (int atomics), 4 edges per thread, int4 load.
// ---------------------------------------------------------------------------
__global__ void __launch_bounds__(256) hist32_kernel(
    const int* __restrict__ rows32, int* __restrict__ cnt, int nE) {
    const int base = (blockIdx.x * 256 + threadIdx.x) * 4;
    if (base + 3 < nE) {
        const int4 r = *(const int4*)&rows32[base];
        atomicAdd(&cnt[r.x], 1);
        atomicAdd(&cnt[r.y], 1);
        atomicAdd(&cnt[r.z], 1);
        atomicAdd(&cnt[r.w], 1);
    } else {
        for (int k = 0; k < 4; ++k)
            if (base + k < nE) atomicAdd(&cnt[rows32[base + k]], 1);
    }
}

// ---------------------------------------------------------------------------
// Exclusive scan, hierarchical (1024 elems/block).
// ---------------------------------------------------------------------------
__global__ void __launch_bounds__(256) scan1_kernel(
    const int* __restrict__ cnt, int* __restrict__ cursor,
    int* __restrict__ blksums, int n) {
    __shared__ int tmp[256];
    const int t = threadIdx.x;
    const int base = blockIdx.x * 1024 + t * 4;
    int v0 = (base + 0 < n) ? cnt[base + 0] : 0;
    int v1 = (base + 1 < n) ? cnt[base + 1] : 0;
    int v2 = (base + 2 < n) ? cnt[base + 2] : 0;
    int v3 = (base + 3 < n) ? cnt[base + 3] : 0;
    const int s = v0 + v1 + v2 + v3;
    tmp[t] = s;
    __syncthreads();
    for (int off = 1; off < 256; off <<= 1) {
        int v = 0;
        if (t >= off) v = tmp[t - off];
        __syncthreads();
        tmp[t] += v;
        __syncthreads();
    }
    const int excl = tmp[t] - s;
    if (t == 255) blksums[blockIdx.x] = tmp[255];
    if (base + 0 < n) cursor[base + 0] = excl;
    if (base + 1 < n) cursor[base + 1] = excl + v0;
    if (base + 2 < n) cursor[base + 2] = excl + v0 + v1;
    if (base + 3 < n) cursor[base + 3] = excl + v0 + v1 + v2;
}

__global__ void __launch_bounds__(1024) scan2_kernel(int* __restrict__ blksums, int nblk) {
    __shared__ int tmp[1024];
    const int t = threadIdx.x;
    const int v = (t < nblk) ? blksums[t] : 0;
    tmp[t] = v;
    __syncthreads();
    for (int off = 1; off < 1024; off <<= 1) {
        int u = 0;
        if (t >= off) u = tmp[t - off];
        __syncthreads();
        tmp[t] += u;
        __syncthreads();
    }
    if (t < nblk) blksums[t] = tmp[t] - v;
}

__global__ void __launch_bounds__(256) scan3_kernel(
    int* __restrict__ cursor, const int* __restrict__ blksums, int n) {
    const int add = blksums[blockIdx.x];
    const int base = blockIdx.x * 1024 + threadIdx.x * 4;
    if (base + 0 < n) cursor[base + 0] += add;
    if (base + 1 < n) cursor[base + 1] += add;
    if (base + 2 < n) cursor[base + 2] += add;
    if (base + 3 < n) cursor[base + 3] += add;
}

// ---------------------------------------------------------------------------
// Partitioned CSR build. Partition p = blockIdx & 7 owns rows
// [p*ceil(n/8), (p+1)*ceil(n/8)): its cursor slice and scol segment stay in
// one XCD's L2 (round-robin blockIdx->XCD), so scattered 4B stores coalesce
// in L2 instead of thrashing lines across the fabric. Every edge is committed
// exactly once (by the block whose partition owns its row) regardless of the
// actual XCD mapping. After this kernel, cursor[r] == segment end for row r.
// ---------------------------------------------------------------------------
__global__ void __launch_bounds__(256) build_part32_kernel(
    const int* __restrict__ rows32, const int* __restrict__ cols32,
    int* __restrict__ cursor, int* __restrict__ scol, int nE, int n) {
    const int p  = blockIdx.x & (NPART - 1);
    const int q  = blockIdx.x / NPART;
    const int nq = gridDim.x / NPART;
    const unsigned bound = (unsigned)((n + NPART - 1) / NPART);
    const unsigned lo    = (unsigned)p * bound;
    const int stride = nq * 256;
    for (int e = q * 256 + (int)threadIdx.x; e < nE; e += stride) {
        const int r = rows32[e];
        if ((unsigned)r - lo < bound) {
            const int pos = atomicAdd(&cursor[r], 1);
            scol[pos] = cols32[e];
        }
    }
}

// ---------------------------------------------------------------------------
// Fused gather (fp16) + mean + (row @ W^T + b). One wave per node.
// ---------------------------------------------------------------------------
__global__ void __launch_bounds__(256) gather_finalize_kernel(
    const __half* __restrict__ xh, const int* __restrict__ scol,
    const int* __restrict__ cursor, const int* __restrict__ cnt,
    const float* __restrict__ W, const float* __restrict__ b,
    float* __restrict__ out, int n) {
    __shared__ __align__(16) float rowbuf[4][DIM];
    const int group = threadIdx.x >> 6;
    const int lane  = threadIdx.x & 63;
    const int wid   = (int)((blockIdx.x * blockDim.x + threadIdx.x) >> 6);
    const int nw    = (int)((gridDim.x * blockDim.x) >> 6);

    // wc[k] = W[lane][k]  (thread's output column of W^T)
    float wc[DIM];
    #pragma unroll
    for (int k4 = 0; k4 < DIM / 4; ++k4) {
        float4 w4 = *(const float4*)&W[(size_t)lane * DIM + k4 * 4];
        wc[k4 * 4 + 0] = w4.x; wc[k4 * 4 + 1] = w4.y;
        wc[k4 * 4 + 2] = w4.z; wc[k4 * 4 + 3] = w4.w;
    }
    const float bl = b[lane];

    for (int r = wid; r < n; r += nw) {
        const int k   = cnt[r];
        const int end = cursor[r];
        const int s   = end - k;
        float a0 = 0.0f, a1 = 0.0f;
        int j = 0;
        for (; j + 3 < k; j += 4) {
            const int c0 = scol[s + j + 0];
            const int c1 = scol[s + j + 1];
            const int c2 = scol[s + j + 2];
            const int c3 = scol[s + j + 3];
            const float v0 = __half2float(xh[(size_t)c0 * DIM + lane]);
            const float v1 = __half2float(xh[(size_t)c1 * DIM + lane]);
            const float v2 = __half2float(xh[(size_t)c2 * DIM + lane]);
            const float v3 = __half2float(xh[(size_t)c3 * DIM + lane]);
            a0 += v0; a1 += v1; a0 += v2; a1 += v3;
        }
        for (; j < k; ++j) {
            const int c = scol[s + j];
            a0 += __half2float(xh[(size_t)c * DIM + lane]);
        }
        const float dg   = (k > 0) ? (float)k : 1.0f;
        const float mean = (a0 + a1) / dg;

        rowbuf[group][lane] = mean;   // per-wave broadcast; DS ops in wave order
        float dot = bl;
        #pragma unroll
        for (int k4 = 0; k4 < DIM / 4; ++k4) {
            const float4 m4 = *(const float4*)&rowbuf[group][k4 * 4];
            dot += m4.x * wc[k4 * 4 + 0];
            dot += m4.y * wc[k4 * 4 + 1];
            dot += m4.z * wc[k4 * 4 + 2];
            dot += m4.w * wc[k4 * 4 + 3];
        }
        out[(size_t)r * DIM + lane] = dot;
    }
}

// ---------------------------------------------------------------------------
// Tier-B fallback kernels (round-3 path): read edge_index directly.
// ---------------------------------------------------------------------------
__global__ void __launch_bounds__(256) hist_kernel(
    const void* __restrict__ eiv, int* __restrict__ cnt,
    int nE, const int* __restrict__ flag) {
    const int base = (blockIdx.x * 256 + threadIdx.x) * 4;
    if (base >= nE) return;
    if (*flag) {
        const long long* ei = (const long long*)eiv;
        #pragma unroll
        for (int k = 0; k < 4; ++k)
            if (base + k < nE) atomicAdd(&cnt[(int)ei[base + k]], 1);
    } else {
        const int* ei = (const int*)eiv;
        #pragma unroll
        for (int k = 0; k < 4; ++k)
            if (base + k < nE) atomicAdd(&cnt[ei[base + k]], 1);
    }
}

__global__ void __launch_bounds__(256) build_part_ei_kernel(
    const void* __restrict__ eiv, int* __restrict__ cursor,
    int* __restrict__ scol, int nE, int n, const int* __restrict__ flag) {
    const int p  = blockIdx.x & (NPART - 1);
    const int q  = blockIdx.x / NPART;
    const int nq = gridDim.x / NPART;
    const unsigned bound = (unsigned)((n + NPART - 1) / NPART);
    const unsigned lo    = (unsigned)p * bound;
    const int stride = nq * 256;
    const int is64 = *flag;
    if (is64) {
        const long long* ei = (const long long*)eiv;
        for (int e = q * 256 + (int)threadIdx.x; e < nE; e += stride) {
            const int r = (int)ei[e];
            if ((unsigned)r - lo < bound) {
                const int pos = atomicAdd(&cursor[r], 1);
                scol[pos] = (int)ei[nE + e];
            }
        }
    } else {
        const int* ei = (const int*)eiv;
        for (int e = q * 256 + (int)threadIdx.x; e < nE; e += stride) {
            const int r = ei[e];
            if ((unsigned)r - lo < bound) {
                const int pos = atomicAdd(&cursor[r], 1);
                scol[pos] = ei[nE + e];
            }
        }
    }
}

// f32 gather variant (tier C: ws can't hold xh)
__global__ void __launch_bounds__(256) gather_finalize_f32_kernel(
    const float* __restrict__ x, const int* __restrict__ scol,
    const int* __restrict__ cursor, const int* __restrict__ cnt,
    const float* __restrict__ W, const float* __restrict__ b,
    float* __restrict__ out, int n) {
    __shared__ __align__(16) float rowbuf[4][DIM];
    const int group = threadIdx.x >> 6;
    const int lane  = threadIdx.x & 63;
    const int wid   = (int)((blockIdx.x * blockDim.x + threadIdx.x) >> 6);
    const int nw    = (int)((gridDim.x * blockDim.x) >> 6);
    float wc[DIM];
    #pragma unroll
    for (int k4 = 0; k4 < DIM / 4; ++k4) {
        float4 w4 = *(const float4*)&W[(size_t)lane * DIM + k4 * 4];
        wc[k4 * 4 + 0] = w4.x; wc[k4 * 4 + 1] = w4.y;
        wc[k4 * 4 + 2] = w4.z; wc[k4 * 4 + 3] = w4.w;
    }
    const float bl = b[lane];
    for (int r = wid; r < n; r += nw) {
        const int k   = cnt[r];
        const int end = cursor[r];
        const int s   = end - k;
        float a0 = 0.0f, a1 = 0.0f;
        int j = 0;
        for (; j + 3 < k; j += 4) {
            a0 += x[(size_t)scol[s + j + 0] * DIM + lane];
            a1 += x[(size_t)scol[s + j + 1] * DIM + lane];
            a0 += x[(size_t)scol[s + j + 2] * DIM + lane];
            a1 += x[(size_t)scol[s + j + 3] * DIM + lane];
        }
        for (; j < k; ++j) a0 += x[(size_t)scol[s + j] * DIM + lane];
        const float dg   = (k > 0) ? (float)k : 1.0f;
        const float mean = (a0 + a1) / dg;
        rowbuf[group][lane] = mean;
        float dot = bl;
        #pragma unroll
        for (int k4 = 0; k4 < DIM / 4; ++k4) {
            const float4 m4 = *(const float4*)&rowbuf[group][k4 * 4];
            dot += m4.x * wc[k4 * 4 + 0];
            dot += m4.y * wc[k4 * 4 + 1];
            dot += m4.z * wc[k4 * 4 + 2];
            dot += m4.w * wc[k4 * 4 + 3];
        }
        out[(size_t)r * DIM + lane] = dot;
    }
}

extern "C" void kernel_launch(void* const* d_in, const int* in_sizes, int n_in,
                              void* d_out, int out_size, void* d_ws, size_t ws_size,
                              hipStream_t stream) {
    const float* x  = (const float*)d_in[0];
    const void*  ei = (const void*)d_in[1];
    const float* W  = (const float*)d_in[2];
    const float* b  = (const float*)d_in[3];
    float* out = (float*)d_out;

    const int n  = in_sizes[0] / DIM;   // 100000
    const int nE = in_sizes[1] / 2;     // 1600000

    // ws layout (4B units):
    //   cnt[n] | cursor[n] | blksums[1024] | flag[64] | scol[nE] |
    //   xh[n*DIM/2] | rows32[nE] | cols32[nE]
    int* wsI     = (int*)d_ws;
    int* cnt     = wsI;
    int* cursor  = wsI + n;
    int* blksums = wsI + 2 * n;
    int* flag    = wsI + 2 * n + 1024;
    int* scol    = wsI + 2 * n + 1088;
    __half* xh   = (__half*)(wsI + 2 * n + 1088 + nE);
    int* rows32  = wsI + 2 * n + 1088 + nE + n * (DIM / 2);
    int* cols32  = rows32 + nE;

    const size_t need_csr  = ((size_t)2 * n + 1088 + (size_t)nE) * sizeof(int);
    const size_t need_fp16 = need_csr + (size_t)n * DIM * sizeof(__half);
    const size_t need_full = need_fp16 + (size_t)2 * nE * sizeof(int);

    if (ws_size < need_csr) return;  // no viable path (shouldn't happen)

    const int nblk = (n + 1023) / 1024;
    const bool fp16 = (ws_size >= need_fp16);
    const bool full = (ws_size >= need_full);

    detect_kernel<<<1, 64, 0, stream>>>((const unsigned int*)ei, flag);
    hipMemsetAsync(cnt, 0, (size_t)n * sizeof(int), stream);
    if (fp16) {
        const int n4 = n * DIM / 4;
        convert_kernel<<<(n4 + 255) / 256, 256, 0, stream>>>(
            (const float4*)x, (ushort4*)xh, n4);
    }

    if (full) {
        cvt_idx_kernel<<<(nE + 255) / 256, 256, 0, stream>>>(ei, rows32, cols32, nE, flag);
        hist32_kernel<<<(nE / 4 + 255) / 256, 256, 0, stream>>>(rows32, cnt, nE);
    } else {
        hist_kernel<<<(nE / 4 + 255) / 256, 256, 0, stream>>>(ei, cnt, nE, flag);
    }

    scan1_kernel<<<nblk, 256, 0, stream>>>(cnt, cursor, blksums, n);
    scan2_kernel<<<1, 1024, 0, stream>>>(blksums, nblk);
    scan3_kernel<<<nblk, 256, 0, stream>>>(cursor, blksums, n);

    if (full) {
        build_part32_kernel<<<2048, 256, 0, stream>>>(rows32, cols32, cursor, scol, nE, n);
    } else {
        build_part_ei_kernel<<<2048, 256, 0, stream>>>(ei, cursor, scol, nE, n, flag);
    }

    if (fp16) {
        gather_finalize_kernel<<<2048, 256, 0, stream>>>(xh, scol, cursor, cnt, W, b, out, n);
    } else {
        gather_finalize_f32_kernel<<<2048, 256, 0, stream>>>(x, scol, cursor, cnt, W, b, out, n);
    }
}

// Round 5
// 307.068 us; speedup vs baseline: 1.3141x; 1.1492x over previous
//
#include <hip/hip_runtime.h>
#include <hip/hip_bf16.h>
#include <hip/hip_fp16.h>

#define DIM 64
#define NPART 8

typedef _Float16 half2_t __attribute__((ext_vector_type(2)));

#if defined(__has_builtin)
#if __has_builtin(__builtin_amdgcn_fdot2)
#define HAVE_FDOT2 1
#endif
#endif

__device__ __forceinline__ float dot2acc(unsigned int mu, unsigned int wu, float acc) {
#ifdef HAVE_FDOT2
    return __builtin_amdgcn_fdot2(__builtin_bit_cast(half2_t, mu),
                                  __builtin_bit_cast(half2_t, wu), acc, false);
#else
    const float2 mf = __half22float2(*(const __half2*)&mu);
    const float2 wf = __half22float2(*(const __half2*)&wu);
    return acc + mf.x * wf.x + mf.y * wf.y;
#endif
}

// ---------------------------------------------------------------------------
// Detect int64 vs int32 edge_index (one wave, one ballot).
// ---------------------------------------------------------------------------
__global__ void detect_kernel(const unsigned int* __restrict__ ei, int* __restrict__ flag) {
    const int lane = threadIdx.x & 63;
    const unsigned int hi = ei[2 * lane + 1];
    const unsigned long long ball = __ballot(hi != 0u);
    if (threadIdx.x == 0) *flag = (ball == 0ULL) ? 1 : 0;
}

// ---------------------------------------------------------------------------
// Convert x (f32) -> xh (fp16), vectorized.
// ---------------------------------------------------------------------------
__global__ void __launch_bounds__(256) convert_kernel(
    const float4* __restrict__ x, ushort4* __restrict__ xh, int n4) {
    const int i = blockIdx.x * 256 + threadIdx.x;
    if (i >= n4) return;
    const float4 v = x[i];
    ushort4 o;
    o.x = __half_as_ushort(__float2half(v.x));
    o.y = __half_as_ushort(__float2half(v.y));
    o.z = __half_as_ushort(__float2half(v.z));
    o.w = __half_as_ushort(__float2half(v.w));
    xh[i] = o;
}

// ---------------------------------------------------------------------------
// Convert W (f32, 64x64) -> packed half2 per uint (row-major, 64 rows x 32).
// ---------------------------------------------------------------------------
__global__ void __launch_bounds__(256) cvtW_kernel(
    const float* __restrict__ W, unsigned int* __restrict__ wh2, int n2) {
    const int i = blockIdx.x * 256 + threadIdx.x;
    if (i >= n2) return;
    const float2 f = ((const float2*)W)[i];
    const __half2 h = __floats2half2_rn(f.x, f.y);
    wh2[i] = *(const unsigned int*)&h;
}

// ---------------------------------------------------------------------------
// Fused edge-index convert + row histogram. 4 edges/thread.
// ---------------------------------------------------------------------------
__global__ void __launch_bounds__(256) prep_kernel(
    const void* __restrict__ eiv, int* __restrict__ rows32, int* __restrict__ cols32,
    int* __restrict__ cnt, int nE, const int* __restrict__ flag) {
    const int base = (blockIdx.x * 256 + threadIdx.x) * 4;
    if (base >= nE) return;
    if (base + 3 < nE) {
        int4 rr, cc;
        if (*flag) {
            const long long* ei = (const long long*)eiv;
            const longlong2 r01 = *(const longlong2*)&ei[base];
            const longlong2 r23 = *(const longlong2*)&ei[base + 2];
            const longlong2 c01 = *(const longlong2*)&ei[nE + base];
            const longlong2 c23 = *(const longlong2*)&ei[nE + base + 2];
            rr = make_int4((int)r01.x, (int)r01.y, (int)r23.x, (int)r23.y);
            cc = make_int4((int)c01.x, (int)c01.y, (int)c23.x, (int)c23.y);
        } else {
            const int* ei = (const int*)eiv;
            rr = *(const int4*)&ei[base];
            cc = *(const int4*)&ei[nE + base];
        }
        *(int4*)&rows32[base] = rr;
        *(int4*)&cols32[base] = cc;
        atomicAdd(&cnt[rr.x], 1);
        atomicAdd(&cnt[rr.y], 1);
        atomicAdd(&cnt[rr.z], 1);
        atomicAdd(&cnt[rr.w], 1);
    } else {
        for (int k = 0; k < 4 && base + k < nE; ++k) {
            int r, c;
            if (*flag) {
                const long long* ei = (const long long*)eiv;
                r = (int)ei[base + k]; c = (int)ei[nE + base + k];
            } else {
                const int* ei = (const int*)eiv;
                r = ei[base + k]; c = ei[nE + base + k];
            }
            rows32[base + k] = r;
            cols32[base + k] = c;
            atomicAdd(&cnt[r], 1);
        }
    }
}

// ---------------------------------------------------------------------------
// Exclusive scan, hierarchical (1024 elems/block).
// ---------------------------------------------------------------------------
__global__ void __launch_bounds__(256) scan1_kernel(
    const int* __restrict__ cnt, int* __restrict__ cursor,
    int* __restrict__ blksums, int n) {
    __shared__ int tmp[256];
    const int t = threadIdx.x;
    const int base = blockIdx.x * 1024 + t * 4;
    int v0 = (base + 0 < n) ? cnt[base + 0] : 0;
    int v1 = (base + 1 < n) ? cnt[base + 1] : 0;
    int v2 = (base + 2 < n) ? cnt[base + 2] : 0;
    int v3 = (base + 3 < n) ? cnt[base + 3] : 0;
    const int s = v0 + v1 + v2 + v3;
    tmp[t] = s;
    __syncthreads();
    for (int off = 1; off < 256; off <<= 1) {
        int v = 0;
        if (t >= off) v = tmp[t - off];
        __syncthreads();
        tmp[t] += v;
        __syncthreads();
    }
    const int excl = tmp[t] - s;
    if (t == 255) blksums[blockIdx.x] = tmp[255];
    if (base + 0 < n) cursor[base + 0] = excl;
    if (base + 1 < n) cursor[base + 1] = excl + v0;
    if (base + 2 < n) cursor[base + 2] = excl + v0 + v1;
    if (base + 3 < n) cursor[base + 3] = excl + v0 + v1 + v2;
}

__global__ void __launch_bounds__(1024) scan2_kernel(int* __restrict__ blksums, int nblk) {
    __shared__ int tmp[1024];
    const int t = threadIdx.x;
    const int v = (t < nblk) ? blksums[t] : 0;
    tmp[t] = v;
    __syncthreads();
    for (int off = 1; off < 1024; off <<= 1) {
        int u = 0;
        if (t >= off) u = tmp[t - off];
        __syncthreads();
        tmp[t] += u;
        __syncthreads();
    }
    if (t < nblk) blksums[t] = tmp[t] - v;
}

__global__ void __launch_bounds__(256) scan3_kernel(
    int* __restrict__ cursor, const int* __restrict__ blksums, int n) {
    const int add = blksums[blockIdx.x];
    const int base = blockIdx.x * 1024 + threadIdx.x * 4;
    if (base + 0 < n) cursor[base + 0] += add;
    if (base + 1 < n) cursor[base + 1] += add;
    if (base + 2 < n) cursor[base + 2] += add;
    if (base + 3 < n) cursor[base + 3] += add;
}

// ---------------------------------------------------------------------------
// Partitioned CSR build (XCD-local cursor slices / scol segments).
// After this kernel, cursor[r] == segment end for row r.
// ---------------------------------------------------------------------------
__global__ void __launch_bounds__(256) build_part32_kernel(
    const int* __restrict__ rows32, const int* __restrict__ cols32,
    int* __restrict__ cursor, int* __restrict__ scol, int nE, int n) {
    const int p  = blockIdx.x & (NPART - 1);
    const int q  = blockIdx.x / NPART;
    const int nq = gridDim.x / NPART;
    const unsigned bound = (unsigned)((n + NPART - 1) / NPART);
    const unsigned lo    = (unsigned)p * bound;
    const int stride = nq * 256;
    for (int e = q * 256 + (int)threadIdx.x; e < nE; e += stride) {
        const int r = rows32[e];
        if ((unsigned)r - lo < bound) {
            const int pos = atomicAdd(&cursor[r], 1);
            scol[pos] = cols32[e];
        }
    }
}

// ---------------------------------------------------------------------------
// Fused gather (fp16, quarter-wave: 4 rows per VMEM) + mean + dot(W fp16 in
// pinned VGPRs via v_dot2_f32_f16) + bias. One wave per node.
// ---------------------------------------------------------------------------
__global__ void __launch_bounds__(256) gather_finalize_q_kernel(
    const __half* __restrict__ xh, const int* __restrict__ scol,
    const int* __restrict__ cursor, const int* __restrict__ cnt,
    const unsigned int* __restrict__ wh2, const float* __restrict__ b,
    float* __restrict__ out, int n) {
    __shared__ __align__(16) unsigned int rowh[4][32];   // fp16 mean row per wave
    const int tid   = threadIdx.x;
    const int group = tid >> 6;
    const int lane  = tid & 63;
    const int q     = lane >> 4;       // quarter-wave 0..3
    const int s16   = lane & 15;       // lane in quarter; owns features 4*s16..+3
    const int wid   = (int)((blockIdx.x * 256 + tid) >> 6);
    const int nw    = (int)((gridDim.x * 256) >> 6);

    // Pin this lane's W row (64 fp16 = 32 packed uints) in VGPRs. The empty
    // asm makes each value opaque so the compiler cannot re-load W per node.
    unsigned int wcu[32];
    #pragma unroll
    for (int i = 0; i < 32; ++i) wcu[i] = wh2[lane * 32 + i];
    #pragma unroll
    for (int i = 0; i < 32; ++i) asm volatile("" : "+v"(wcu[i]));

    const float bl = b[lane];

    for (int r0 = wid; r0 < n; r0 += nw) {
        const int r   = __builtin_amdgcn_readfirstlane(r0);
        const int k   = cnt[r];
        const int end = cursor[r];
        const int s   = end - k;
        float a0 = 0.f, a1 = 0.f, a2 = 0.f, a3 = 0.f;
        int j = 0;
        for (; j + 7 < k; j += 8) {            // 8 edges in flight (2/quarter)
            const int cA = scol[s + j + q];
            const int cB = scol[s + j + 4 + q];
            const uint2 uA = *(const uint2*)(xh + ((size_t)cA << 6) + (s16 << 2));
            const uint2 uB = *(const uint2*)(xh + ((size_t)cB << 6) + (s16 << 2));
            float2 f;
            f = __half22float2(*(const __half2*)&uA.x); a0 += f.x; a1 += f.y;
            f = __half22float2(*(const __half2*)&uA.y); a2 += f.x; a3 += f.y;
            f = __half22float2(*(const __half2*)&uB.x); a0 += f.x; a1 += f.y;
            f = __half22float2(*(const __half2*)&uB.y); a2 += f.x; a3 += f.y;
        }
        if (j + 3 < k) {                       // one 4-edge step
            const int cA = scol[s + j + q];
            const uint2 uA = *(const uint2*)(xh + ((size_t)cA << 6) + (s16 << 2));
            float2 f;
            f = __half22float2(*(const __half2*)&uA.x); a0 += f.x; a1 += f.y;
            f = __half22float2(*(const __half2*)&uA.y); a2 += f.x; a3 += f.y;
            j += 4;
        }
        for (; j < k; ++j) {                   // <=3 tail edges: quarter 0 only
            const int c = scol[s + j];
            if (q == 0) {
                const uint2 u = *(const uint2*)(xh + ((size_t)c << 6) + (s16 << 2));
                float2 f;
                f = __half22float2(*(const __half2*)&u.x); a0 += f.x; a1 += f.y;
                f = __half22float2(*(const __half2*)&u.y); a2 += f.x; a3 += f.y;
            }
        }
        // reduce across the 4 quarter-waves
        a0 += __shfl_xor(a0, 16); a0 += __shfl_xor(a0, 32);
        a1 += __shfl_xor(a1, 16); a1 += __shfl_xor(a1, 32);
        a2 += __shfl_xor(a2, 16); a2 += __shfl_xor(a2, 32);
        a3 += __shfl_xor(a3, 16); a3 += __shfl_xor(a3, 32);
        const float inv = 1.0f / ((k > 0) ? (float)k : 1.0f);
        if (q == 0) {                          // 16 lanes publish the mean row (fp16)
            const __half2 m01 = __floats2half2_rn(a0 * inv, a1 * inv);
            const __half2 m23 = __floats2half2_rn(a2 * inv, a3 * inv);
            uint2 mu;
            mu.x = *(const unsigned int*)&m01;
            mu.y = *(const unsigned int*)&m23;
            *(uint2*)&rowh[group][s16 * 2] = mu;   // same-wave DS ordering
        }
        float dot = bl;
        #pragma unroll
        for (int i4 = 0; i4 < 8; ++i4) {       // 8 x uniform ds_read_b128
            const uint4 mm = *(const uint4*)&rowh[group][i4 * 4];
            dot = dot2acc(mm.x, wcu[i4 * 4 + 0], dot);
            dot = dot2acc(mm.y, wcu[i4 * 4 + 1], dot);
            dot = dot2acc(mm.z, wcu[i4 * 4 + 2], dot);
            dot = dot2acc(mm.w, wcu[i4 * 4 + 3], dot);
        }
        out[(size_t)r * DIM + lane] = dot;
    }
}

// ---------------------------------------------------------------------------
// Fallback tier (small ws): direct-ei hist/build + f32 gather (round-2 style).
// ---------------------------------------------------------------------------
__global__ void __launch_bounds__(256) hist_kernel(
    const void* __restrict__ eiv, int* __restrict__ cnt,
    int nE, const int* __restrict__ flag) {
    const int base = (blockIdx.x * 256 + threadIdx.x) * 4;
    if (base >= nE) return;
    if (*flag) {
        const long long* ei = (const long long*)eiv;
        #pragma unroll
        for (int k = 0; k < 4; ++k)
            if (base + k < nE) atomicAdd(&cnt[(int)ei[base + k]], 1);
    } else {
        const int* ei = (const int*)eiv;
        #pragma unroll
        for (int k = 0; k < 4; ++k)
            if (base + k < nE) atomicAdd(&cnt[ei[base + k]], 1);
    }
}

__global__ void __launch_bounds__(256) build_part_ei_kernel(
    const void* __restrict__ eiv, int* __restrict__ cursor,
    int* __restrict__ scol, int nE, int n, const int* __restrict__ flag) {
    const int p  = blockIdx.x & (NPART - 1);
    const int q  = blockIdx.x / NPART;
    const int nq = gridDim.x / NPART;
    const unsigned bound = (unsigned)((n + NPART - 1) / NPART);
    const unsigned lo    = (unsigned)p * bound;
    const int stride = nq * 256;
    if (*flag) {
        const long long* ei = (const long long*)eiv;
        for (int e = q * 256 + (int)threadIdx.x; e < nE; e += stride) {
            const int r = (int)ei[e];
            if ((unsigned)r - lo < bound) {
                const int pos = atomicAdd(&cursor[r], 1);
                scol[pos] = (int)ei[nE + e];
            }
        }
    } else {
        const int* ei = (const int*)eiv;
        for (int e = q * 256 + (int)threadIdx.x; e < nE; e += stride) {
            const int r = ei[e];
            if ((unsigned)r - lo < bound) {
                const int pos = atomicAdd(&cursor[r], 1);
                scol[pos] = ei[nE + e];
            }
        }
    }
}

__global__ void __launch_bounds__(256) gather_finalize_f32_kernel(
    const float* __restrict__ x, const int* __restrict__ scol,
    const int* __restrict__ cursor, const int* __restrict__ cnt,
    const float* __restrict__ W, const float* __restrict__ b,
    float* __restrict__ out, int n) {
    __shared__ __align__(16) float rowbuf[4][DIM];
    const int group = threadIdx.x >> 6;
    const int lane  = threadIdx.x & 63;
    const int wid   = (int)((blockIdx.x * blockDim.x + threadIdx.x) >> 6);
    const int nw    = (int)((gridDim.x * blockDim.x) >> 6);
    float wc[DIM];
    #pragma unroll
    for (int k4 = 0; k4 < DIM / 4; ++k4) {
        float4 w4 = *(const float4*)&W[(size_t)lane * DIM + k4 * 4];
        wc[k4 * 4 + 0] = w4.x; wc[k4 * 4 + 1] = w4.y;
        wc[k4 * 4 + 2] = w4.z; wc[k4 * 4 + 3] = w4.w;
    }
    const float bl = b[lane];
    for (int r = wid; r < n; r += nw) {
        const int k   = cnt[r];
        const int end = cursor[r];
        const int s   = end - k;
        float a0 = 0.0f, a1 = 0.0f;
        int j = 0;
        for (; j + 3 < k; j += 4) {
            a0 += x[(size_t)scol[s + j + 0] * DIM + lane];
            a1 += x[(size_t)scol[s + j + 1] * DIM + lane];
            a0 += x[(size_t)scol[s + j + 2] * DIM + lane];
            a1 += x[(size_t)scol[s + j + 3] * DIM + lane];
        }
        for (; j < k; ++j) a0 += x[(size_t)scol[s + j] * DIM + lane];
        const float dg   = (k > 0) ? (float)k : 1.0f;
        const float mean = (a0 + a1) / dg;
        rowbuf[group][lane] = mean;
        float dot = bl;
        #pragma unroll
        for (int k4 = 0; k4 < DIM / 4; ++k4) {
            const float4 m4 = *(const float4*)&rowbuf[group][k4 * 4];
            dot += m4.x * wc[k4 * 4 + 0];
            dot += m4.y * wc[k4 * 4 + 1];
            dot += m4.z * wc[k4 * 4 + 2];
            dot += m4.w * wc[k4 * 4 + 3];
        }
        out[(size_t)r * DIM + lane] = dot;
    }
}

extern "C" void kernel_launch(void* const* d_in, const int* in_sizes, int n_in,
                              void* d_out, int out_size, void* d_ws, size_t ws_size,
                              hipStream_t stream) {
    const float* x  = (const float*)d_in[0];
    const void*  ei = (const void*)d_in[1];
    const float* W  = (const float*)d_in[2];
    const float* b  = (const float*)d_in[3];
    float* out = (float*)d_out;

    const int n  = in_sizes[0] / DIM;   // 100000
    const int nE = in_sizes[1] / 2;     // 1600000

    // ws layout (4B units):
    //   cnt[n] | cursor[n] | blksums[1024] | flag[64] | scol[nE] |
    //   xh[n*DIM/2 halves] | rows32[nE] | cols32[nE] | wh2[DIM*DIM/2]
    int* wsI     = (int*)d_ws;
    int* cnt     = wsI;
    int* cursor  = wsI + n;
    int* blksums = wsI + 2 * n;
    int* flag    = wsI + 2 * n + 1024;
    int* scol    = wsI + 2 * n + 1088;
    __half* xh   = (__half*)(scol + nE);
    int* rows32  = scol + nE + n * (DIM / 2);
    int* cols32  = rows32 + nE;
    unsigned int* wh2 = (unsigned int*)(cols32 + nE);

    const size_t need_csr  = ((size_t)2 * n + 1088 + (size_t)nE) * sizeof(int);
    const size_t need_full = need_csr + (size_t)n * DIM * sizeof(__half)
                           + (size_t)2 * nE * sizeof(int)
                           + (size_t)(DIM * DIM / 2) * sizeof(int);

    if (ws_size < need_csr) return;  // no viable path (shouldn't happen)

    const int nblk = (n + 1023) / 1024;
    const bool full = (ws_size >= need_full);

    detect_kernel<<<1, 64, 0, stream>>>((const unsigned int*)ei, flag);
    hipMemsetAsync(cnt, 0, (size_t)n * sizeof(int), stream);

    if (full) {
        const int n4 = n * DIM / 4;
        convert_kernel<<<(n4 + 255) / 256, 256, 0, stream>>>(
            (const float4*)x, (ushort4*)xh, n4);
        cvtW_kernel<<<(DIM * DIM / 2 + 255) / 256, 256, 0, stream>>>(W, wh2, DIM * DIM / 2);
        prep_kernel<<<(nE / 4 + 255) / 256, 256, 0, stream>>>(ei, rows32, cols32, cnt, nE, flag);
    } else {
        hist_kernel<<<(nE / 4 + 255) / 256, 256, 0, stream>>>(ei, cnt, nE, flag);
    }

    scan1_kernel<<<nblk, 256, 0, stream>>>(cnt, cursor, blksums, n);
    scan2_kernel<<<1, 1024, 0, stream>>>(blksums, nblk);
    scan3_kernel<<<nblk, 256, 0, stream>>>(cursor, blksums, n);

    if (full) {
        build_part32_kernel<<<2048, 256, 0, stream>>>(rows32, cols32, cursor, scol, nE, n);
        gather_finalize_q_kernel<<<2048, 256, 0, stream>>>(xh, scol, cursor, cnt, wh2, b, out, n);
    } else {
        build_part_ei_kernel<<<2048, 256, 0, stream>>>(ei, cursor, scol, nE, n, flag);
        gather_finalize_f32_kernel<<<2048, 256, 0, stream>>>(x, scol, cursor, cnt, W, b, out, n);
    }
}